// Round 12
// baseline (331.521 us; speedup 1.0000x reference)
//
#include <hip/hip_runtime.h>

#define N_NODES 100000
#define N_EDGES 1600000
#define IN_DIM 128
#define DIM_H 64
#define N_GRAPHS 64

#define BKT_BITS 9
#define BKT_SIZE 512
#define NBUCKET ((N_NODES + BKT_SIZE - 1) / BKT_SIZE)  /* 196 */
#define NBLK 256
#define EPB ((N_EDGES + NBLK - 1) / NBLK)              /* 6250 */

__device__ __forceinline__ float relu(float v) { return v > 0.f ? v : 0.f; }
#define BN_SCALE 0.99999500003749968f  /* 1/sqrt(1+1e-5) */

typedef __attribute__((ext_vector_type(8))) short bf16x8;
typedef __attribute__((ext_vector_type(4))) float f32x4;

__device__ __forceinline__ float bf2f(unsigned short u) {
  return __uint_as_float(((unsigned int)u) << 16);
}
__device__ __forceinline__ unsigned short f2bf(float f) {
  unsigned int u = __float_as_uint(f);
  u += 0x7FFFu + ((u >> 16) & 1u);   // round-to-nearest-even
  return (unsigned short)(u >> 16);
}

// ---------------- CSR build: 3-phase counting sort, per-WAVE histograms ----------------
__global__ __launch_bounds__(256) void edge_count(const int* __restrict__ dst,
                                                  int* __restrict__ cnt) {
  __shared__ int hist[4 * NBUCKET];
  int tid = threadIdx.x, blk = blockIdx.x;
  for (int i = tid; i < 4 * NBUCKET; i += 256) hist[i] = 0;
  __syncthreads();
  int* h = hist + (tid >> 6) * NBUCKET;
  int beg = blk * EPB, end = beg + EPB > N_EDGES ? N_EDGES : beg + EPB;
  for (int i = beg + tid; i < end; i += 256) atomicAdd(&h[dst[i] >> BKT_BITS], 1);
  __syncthreads();
  for (int i = tid; i < 4 * NBUCKET; i += 256) cnt[blk * 4 * NBUCKET + i] = hist[i];
}

__global__ __launch_bounds__(256) void col_scan(int* __restrict__ cnt,
                                                int* __restrict__ tot) {
  __shared__ int sd[256];
  int b = blockIdx.x, tid = threadIdx.x;
  int v0 = cnt[(4 * tid + 0) * NBUCKET + b];
  int v1 = cnt[(4 * tid + 1) * NBUCKET + b];
  int v2 = cnt[(4 * tid + 2) * NBUCKET + b];
  int v3 = cnt[(4 * tid + 3) * NBUCKET + b];
  int s = v0 + v1 + v2 + v3;
  sd[tid] = s;
  __syncthreads();
  for (int off = 1; off < 256; off <<= 1) {
    int t = (tid >= off) ? sd[tid - off] : 0;
    __syncthreads();
    sd[tid] += t;
    __syncthreads();
  }
  int excl = sd[tid] - s;
  cnt[(4 * tid + 0) * NBUCKET + b] = excl;
  cnt[(4 * tid + 1) * NBUCKET + b] = excl + v0;
  cnt[(4 * tid + 2) * NBUCKET + b] = excl + v0 + v1;
  cnt[(4 * tid + 3) * NBUCKET + b] = excl + v0 + v1 + v2;
  if (tid == 255) tot[b] = sd[255];
}

__global__ void base_scan(const int* __restrict__ tot, int* __restrict__ base) {
  __shared__ int sd[256];
  int tid = threadIdx.x;
  int v = (tid < NBUCKET) ? tot[tid] : 0;
  sd[tid] = v;
  __syncthreads();
  for (int off = 1; off < 256; off <<= 1) {
    int t = (tid >= off) ? sd[tid - off] : 0;
    __syncthreads();
    sd[tid] += t;
    __syncthreads();
  }
  if (tid < NBUCKET) base[tid] = sd[tid] - v;
}

__global__ __launch_bounds__(256) void edge_place(const int* __restrict__ src,
                                                  const int* __restrict__ dst,
                                                  const int* __restrict__ cnt,
                                                  const int* __restrict__ base,
                                                  int* __restrict__ bktbuf) {
  __shared__ int curs[4 * NBUCKET];
  int tid = threadIdx.x, blk = blockIdx.x;
  for (int i = tid; i < 4 * NBUCKET; i += 256)
    curs[i] = base[i % NBUCKET] + cnt[blk * 4 * NBUCKET + i];
  __syncthreads();
  int* cw = curs + (tid >> 6) * NBUCKET;
  int beg = blk * EPB, end = beg + EPB > N_EDGES ? N_EDGES : beg + EPB;
  for (int i = beg + tid; i < end; i += 256) {
    int d = dst[i];
    int b = d >> BKT_BITS;
    int pos = atomicAdd(&cw[b], 1);
    bktbuf[pos] = src[i] | ((d & (BKT_SIZE - 1)) << 17);
  }
}

__global__ __launch_bounds__(256) void bucket_sort(const int* __restrict__ tot,
                                                   const int* __restrict__ bktbase,
                                                   const int* __restrict__ bktbuf,
                                                   int* __restrict__ rp,
                                                   int* __restrict__ ci) {
  __shared__ int hist[BKT_SIZE];
  __shared__ int partial[256];
  int b = blockIdx.x;
  int tid = threadIdx.x;
  int nb = tot[b];
  int base = bktbase[b];
  const int* buf = bktbuf + base;
  hist[tid] = 0;
  hist[tid + 256] = 0;
  __syncthreads();
  for (int i = tid; i < nb; i += 256) atomicAdd(&hist[buf[i] >> 17], 1);
  __syncthreads();
  int v0 = hist[2 * tid], v1 = hist[2 * tid + 1];
  int s = v0 + v1;
  partial[tid] = s;
  __syncthreads();
  for (int off = 1; off < 256; off <<= 1) {
    int t = (tid >= off) ? partial[tid - off] : 0;
    __syncthreads();
    partial[tid] += t;
    __syncthreads();
  }
  int excl = partial[tid] - s;
  int node0 = b * BKT_SIZE + 2 * tid;
  if (node0 < N_NODES) rp[node0] = base + excl;
  if (node0 + 1 < N_NODES) rp[node0 + 1] = base + excl + v0;
  __syncthreads();
  hist[2 * tid] = excl;
  hist[2 * tid + 1] = excl + v0;
  __syncthreads();
  for (int i = tid; i < nb; i += 256) {
    int p = buf[i];
    int pos = atomicAdd(&hist[p >> 17], 1);
    ci[base + pos] = p & 0x1FFFF;
  }
  if (b == 0 && tid == 0) rp[N_NODES] = N_EDGES;
}

// ---------------- standalone MFMA GEMM (used for proj only) ----------------
template <int KC, int AFP32, int EPI>
__global__ __launch_bounds__(256) void mfma_gemm(const float* __restrict__ af,
                                                 const unsigned short* __restrict__ ab,
                                                 const float* __restrict__ W,
                                                 const float* __restrict__ bias,
                                                 unsigned short* __restrict__ outb) {
  constexpr int K = KC * 32;
  __shared__ unsigned short lw[K * 64];
  int tid = threadIdx.x;
#pragma unroll
  for (int i = 0; i < K * 64 / 256; ++i) {
    int idx = tid + i * 256;
    int k = idx >> 6, o = idx & 63;
    unsigned int boff = (unsigned int)((o * K + k) * 2) ^ ((unsigned int)(o & 7) << 4);
    *(unsigned short*)((char*)lw + boff) = f2bf(W[idx]);
  }
  __syncthreads();
  int lane = tid & 63;
  int wave = tid >> 6;
  int arow = lane & 15;
  int kq = lane >> 4;
  int mb = blockIdx.x * 64 + wave * 16;
  if (mb >= N_NODES) return;
  int anode = mb + arow;
  if (anode >= N_NODES) anode = N_NODES - 1;
  f32x4 acc[4];
#pragma unroll
  for (int t = 0; t < 4; ++t) acc[t] = (f32x4){0.f, 0.f, 0.f, 0.f};
#pragma unroll
  for (int kc = 0; kc < KC; ++kc) {
    bf16x8 afrag;
    if (AFP32) {
      const float* ap = af + (size_t)anode * K + kc * 32 + kq * 8;
      float4 u0 = *(const float4*)(ap);
      float4 u1 = *(const float4*)(ap + 4);
      afrag[0] = (short)f2bf(u0.x); afrag[1] = (short)f2bf(u0.y);
      afrag[2] = (short)f2bf(u0.z); afrag[3] = (short)f2bf(u0.w);
      afrag[4] = (short)f2bf(u1.x); afrag[5] = (short)f2bf(u1.y);
      afrag[6] = (short)f2bf(u1.z); afrag[7] = (short)f2bf(u1.w);
    } else {
      afrag = *(const bf16x8*)(ab + (size_t)anode * K + kc * 32 + kq * 8);
    }
#pragma unroll
    for (int t = 0; t < 4; ++t) {
      int o = t * 16 + (lane & 15);
      unsigned int boff = (unsigned int)((o * K + kc * 32 + kq * 8) * 2) ^
                          ((unsigned int)(o & 7) << 4);
      bf16x8 bfrag = *(const bf16x8*)((char*)lw + boff);
      acc[t] = __builtin_amdgcn_mfma_f32_16x16x32_bf16(afrag, bfrag, acc[t], 0, 0, 0);
    }
  }
  int ccol = lane & 15;
#pragma unroll
  for (int t = 0; t < 4; ++t) {
    int c = t * 16 + ccol;
    float bv = (EPI != 0) ? bias[c] : 0.f;
#pragma unroll
    for (int r = 0; r < 4; ++r) {
      int node = mb + kq * 4 + r;
      if (node < N_NODES) {
        float vv = acc[t][r];
        if (EPI == 1) vv = relu(vv + bv);
        outb[(size_t)node * 64 + c] = f2bf(vv);
      }
    }
  }
}

// ---------------- fused conv layer: agg (+BN if FIRST) + [GEMMa+BN] + GEMMb ----------------
// Block = 4 waves x 16 nodes; everything wave-local after weight staging.
// FIRST: conv0 (BN fused into agg write; single GEMM Wb). LAST: pool epilogue into hp.
template <int FIRST, int LAST>
__global__ __launch_bounds__(256) void conv_fused(
    const unsigned short* __restrict__ hin,
    const int* __restrict__ rp, const int* __restrict__ ci,
    const float* __restrict__ pba, const float* __restrict__ pg,
    const float* __restrict__ pbe,
    const float* __restrict__ Wa, const float* __restrict__ ba2,
    const float* __restrict__ ga, const float* __restrict__ bea,
    const float* __restrict__ Wb, const float* __restrict__ bb,
    unsigned short* __restrict__ hout,
    const int* __restrict__ batch, float* __restrict__ hp) {
  __shared__ unsigned short lwa[FIRST ? 2 : 64 * 64];
  __shared__ unsigned short lwb[64 * 64];
  __shared__ unsigned short zt[4][16 * 64];   // per-wave 16x64 bf16 tile (swizzled)
  int tid = threadIdx.x;
  if (!FIRST) {
#pragma unroll
    for (int i = 0; i < 16; ++i) {
      int idx = tid + i * 256;
      int k = idx >> 6, o = idx & 63;
      unsigned int boff = (unsigned int)((o * 64 + k) * 2) ^ ((unsigned int)(o & 7) << 4);
      *(unsigned short*)((char*)lwa + boff) = f2bf(Wa[idx]);
    }
  }
#pragma unroll
  for (int i = 0; i < 16; ++i) {
    int idx = tid + i * 256;
    int k = idx >> 6, o = idx & 63;
    unsigned int boff = (unsigned int)((o * 64 + k) * 2) ^ ((unsigned int)(o & 7) << 4);
    *(unsigned short*)((char*)lwb + boff) = f2bf(Wb[idx]);
  }
  __syncthreads();
  int lane = tid & 63;
  int wave = tid >> 6;
  int mb = blockIdx.x * 64 + wave * 16;
  if (mb >= N_NODES) return;                 // after the only barrier
  char* zw = (char*)&zt[wave][0];

  // ---- phase A: aggregate 16 nodes (R10 4-edge layout) into LDS tile ----
  int eg = lane >> 4;        // edge subgroup 0..3
  int dq = lane & 15;        // ushort4 slot
  for (int n = 0; n < 16; ++n) {
    int node = mb + n;
    if (node >= N_NODES) node = N_NODES - 1;
    int beg = rp[node], end = rp[node + 1];
    float a0 = 0.f, a1 = 0.f, a2 = 0.f, a3 = 0.f;
    float b0 = 0.f, b1 = 0.f, b2 = 0.f, b3 = 0.f;
    int e = beg;
    for (; e + 8 <= end; e += 8) {
      int i0 = ci[e + eg];
      int i1 = ci[e + 4 + eg];
      ushort4 v0 = *(const ushort4*)(hin + (size_t)i0 * 64 + dq * 4);
      ushort4 v1 = *(const ushort4*)(hin + (size_t)i1 * 64 + dq * 4);
      a0 += bf2f(v0.x); a1 += bf2f(v0.y); a2 += bf2f(v0.z); a3 += bf2f(v0.w);
      b0 += bf2f(v1.x); b1 += bf2f(v1.y); b2 += bf2f(v1.z); b3 += bf2f(v1.w);
    }
    for (; e < end; e += 4) {
      if (e + eg < end) {
        ushort4 v0 = *(const ushort4*)(hin + (size_t)ci[e + eg] * 64 + dq * 4);
        a0 += bf2f(v0.x); a1 += bf2f(v0.y); a2 += bf2f(v0.z); a3 += bf2f(v0.w);
      }
    }
    a0 += b0; a1 += b1; a2 += b2; a3 += b3;
    a0 += __shfl_xor(a0, 16, 64); a1 += __shfl_xor(a1, 16, 64);
    a2 += __shfl_xor(a2, 16, 64); a3 += __shfl_xor(a3, 16, 64);
    a0 += __shfl_xor(a0, 32, 64); a1 += __shfl_xor(a1, 32, 64);
    a2 += __shfl_xor(a2, 32, 64); a3 += __shfl_xor(a3, 32, 64);
    if (eg == 0) {
      ushort4 s = *(const ushort4*)(hin + (size_t)(mb + n < N_NODES ? mb + n : N_NODES - 1) * 64 + dq * 4);
      float r0 = a0 + bf2f(s.x), r1 = a1 + bf2f(s.y);
      float r2 = a2 + bf2f(s.z), r3 = a3 + bf2f(s.w);
      if (FIRST) {
        float4 bav = *(const float4*)(pba + dq * 4);
        float4 gv = *(const float4*)(pg + dq * 4);
        float4 bev = *(const float4*)(pbe + dq * 4);
        r0 = relu(fmaf((r0 + bav.x) * BN_SCALE, gv.x, bev.x));
        r1 = relu(fmaf((r1 + bav.y) * BN_SCALE, gv.y, bev.y));
        r2 = relu(fmaf((r2 + bav.z) * BN_SCALE, gv.z, bev.z));
        r3 = relu(fmaf((r3 + bav.w) * BN_SCALE, gv.w, bev.w));
      }
      ushort4 o;
      o.x = f2bf(r0); o.y = f2bf(r1); o.z = f2bf(r2); o.w = f2bf(r3);
      *(ushort4*)(zw + ((n * 128 + dq * 8) ^ ((n & 7) << 4))) = o;
    }
  }
  // wave-local LDS dependency: compiler inserts lgkmcnt waits; no barrier needed.

  int arow = lane & 15;
  int kq = lane >> 4;
  int ccol = lane & 15;
  f32x4 acc[4];

  // ---- phase B: GEMMa (z @ Wa + ba)*BN relu -> back into tile (skip if FIRST) ----
  if (!FIRST) {
#pragma unroll
    for (int t = 0; t < 4; ++t) acc[t] = (f32x4){0.f, 0.f, 0.f, 0.f};
#pragma unroll
    for (int kc = 0; kc < 2; ++kc) {
      bf16x8 afrag = *(const bf16x8*)(zw + ((arow * 128 + kc * 64 + kq * 16) ^ ((arow & 7) << 4)));
#pragma unroll
      for (int t = 0; t < 4; ++t) {
        int o = t * 16 + ccol;
        unsigned int boff = (unsigned int)((o * 64 + kc * 32 + kq * 8) * 2) ^
                            ((unsigned int)(o & 7) << 4);
        bf16x8 bfrag = *(const bf16x8*)((char*)lwa + boff);
        acc[t] = __builtin_amdgcn_mfma_f32_16x16x32_bf16(afrag, bfrag, acc[t], 0, 0, 0);
      }
    }
#pragma unroll
    for (int t = 0; t < 4; ++t) {
      int c = t * 16 + ccol;
      float bv = ba2[c], gv = ga[c], bev = bea[c];
#pragma unroll
      for (int r = 0; r < 4; ++r) {
        int row = kq * 4 + r;
        float v = relu(fmaf((acc[t][r] + bv) * BN_SCALE, gv, bev));
        *(unsigned short*)(zw + ((row * 128 + c * 2) ^ ((row & 7) << 4))) = f2bf(v);
      }
    }
  }

  // ---- phase C: GEMMb (t @ Wb + bb) relu -> hout or pooled hp ----
#pragma unroll
  for (int t = 0; t < 4; ++t) acc[t] = (f32x4){0.f, 0.f, 0.f, 0.f};
#pragma unroll
  for (int kc = 0; kc < 2; ++kc) {
    bf16x8 afrag = *(const bf16x8*)(zw + ((arow * 128 + kc * 64 + kq * 16) ^ ((arow & 7) << 4)));
#pragma unroll
    for (int t = 0; t < 4; ++t) {
      int o = t * 16 + ccol;
      unsigned int boff = (unsigned int)((o * 64 + kc * 32 + kq * 8) * 2) ^
                          ((unsigned int)(o & 7) << 4);
      bf16x8 bfrag = *(const bf16x8*)((char*)lwb + boff);
      acc[t] = __builtin_amdgcn_mfma_f32_16x16x32_bf16(afrag, bfrag, acc[t], 0, 0, 0);
    }
  }
  if (LAST) {
    int nlast = mb + 15 < N_NODES ? mb + 15 : N_NODES - 1;
    int b0 = batch[mb], b1 = batch[nlast];
    float v[4][4];
#pragma unroll
    for (int t = 0; t < 4; ++t) {
      float bv = bb[t * 16 + ccol];
#pragma unroll
      for (int r = 0; r < 4; ++r) {
        int node = mb + kq * 4 + r;
        v[t][r] = (node < N_NODES) ? relu(acc[t][r] + bv) : 0.f;
      }
    }
    if (b0 == b1) {
#pragma unroll
      for (int t = 0; t < 4; ++t) {
        float s = (v[t][0] + v[t][1]) + (v[t][2] + v[t][3]);
        s += __shfl_xor(s, 16, 64);
        s += __shfl_xor(s, 32, 64);
        if (kq == 0) atomicAdd(&hp[b0 * 64 + t * 16 + ccol], s);
      }
    } else {
      int bn[4];
#pragma unroll
      for (int r = 0; r < 4; ++r) {
        int node = mb + kq * 4 + r;
        bn[r] = batch[node < N_NODES ? node : N_NODES - 1];
      }
#pragma unroll
      for (int t = 0; t < 4; ++t)
#pragma unroll
        for (int r = 0; r < 4; ++r) {
          int node = mb + kq * 4 + r;
          if (node < N_NODES) atomicAdd(&hp[bn[r] * 64 + t * 16 + ccol], v[t][r]);
        }
    }
  } else {
#pragma unroll
    for (int t = 0; t < 4; ++t) {
      int c = t * 16 + ccol;
      float bv = bb[c];
#pragma unroll
      for (int r = 0; r < 4; ++r) {
        int node = mb + kq * 4 + r;
        if (node < N_NODES) hout[(size_t)node * 64 + c] = f2bf(relu(acc[t][r] + bv));
      }
    }
  }
}

// ---------------- classifier ----------------
__global__ __launch_bounds__(64) void cls_kernel(const float* __restrict__ hp,
                                                 const float* __restrict__ Wl1,
                                                 const float* __restrict__ bl1,
                                                 const float* __restrict__ Wl2,
                                                 const float* __restrict__ bl2,
                                                 float* __restrict__ out) {
  int g = blockIdx.x;
  int d = threadIdx.x;
  const float* hrow = hp + g * 64;
  float acc = bl1[d];
#pragma unroll 8
  for (int k = 0; k < 64; ++k) {
    float v = hrow[k];
    float w = Wl1[k * 64 + d] + Wl1[(64 + k) * 64 + d] + Wl1[(128 + k) * 64 + d];
    acc = fmaf(v, w, acc);
  }
  float t = relu(acc);
  float p0 = t * Wl2[d * 2 + 0];
  float p1 = t * Wl2[d * 2 + 1];
#pragma unroll
  for (int off = 32; off > 0; off >>= 1) {
    p0 += __shfl_xor(p0, off, 64);
    p1 += __shfl_xor(p1, off, 64);
  }
  if (d == 0) {
    float z0 = p0 + bl2[0];
    float z1 = p1 + bl2[1];
    float m = fmaxf(z0, z1);
    float lse = m + logf(expf(z0 - m) + expf(z1 - m));
    out[g * 2 + 0] = z0 - lse;
    out[g * 2 + 1] = z1 - lse;
  }
}

extern "C" void kernel_launch(void* const* d_in, const int* in_sizes, int n_in,
                              void* d_out, int out_size, void* d_ws, size_t ws_size,
                              hipStream_t stream) {
  const float* x   = (const float*)d_in[0];
  const int*   ei  = (const int*)d_in[1];
  const int*   bat = (const int*)d_in[2];
  const float* W0a = (const float*)d_in[3];
  const float* b0a = (const float*)d_in[4];
  const float* g0  = (const float*)d_in[5];
  const float* be0 = (const float*)d_in[6];
  const float* W0b = (const float*)d_in[7];
  const float* b0b = (const float*)d_in[8];
  const float* Wsa = (const float*)d_in[9];
  const float* bsa = (const float*)d_in[10];
  const float* gs  = (const float*)d_in[11];
  const float* bes = (const float*)d_in[12];
  const float* Wsb = (const float*)d_in[13];
  const float* bsb = (const float*)d_in[14];
  const float* Wl1 = (const float*)d_in[15];
  const float* bl1 = (const float*)d_in[16];
  const float* Wl2 = (const float*)d_in[17];
  const float* bl2 = (const float*)d_in[18];
  const int* src = ei;
  const int* dst = ei + N_EDGES;

  char* ws = (char*)d_ws;
  size_t off = 0;
  auto alloc = [&](size_t bytes) { void* p = ws + off; off += (bytes + 255) & ~255ull; return p; };
  int* rp      = (int*)alloc((size_t)(N_NODES + 1) * 4);
  int* cnt     = (int*)alloc((size_t)NBLK * 4 * NBUCKET * 4);
  int* tot     = (int*)alloc((size_t)NBUCKET * 4);
  int* bktbase = (int*)alloc((size_t)NBUCKET * 4);
  int* ci      = (int*)alloc((size_t)N_EDGES * 4);
  unsigned short* hA = (unsigned short*)alloc((size_t)N_NODES * 64 * 2);
  unsigned short* hB = (unsigned short*)alloc((size_t)N_NODES * 64 * 2);
  float* hp    = (float*)alloc((size_t)N_GRAPHS * 64 * 4);
  int* bktbuf  = (int*)hB;  // alias: consumed by bucket_sort before hB first written (conv0)

  hipMemsetAsync(hp, 0, (size_t)N_GRAPHS * 64 * 4, stream);

  edge_count<<<NBLK, 256, 0, stream>>>(dst, cnt);
  col_scan<<<NBUCKET, 256, 0, stream>>>(cnt, tot);
  base_scan<<<1, 256, 0, stream>>>(tot, bktbase);
  edge_place<<<NBLK, 256, 0, stream>>>(src, dst, cnt, bktbase, bktbuf);
  bucket_sort<<<NBUCKET, 256, 0, stream>>>(tot, bktbase, bktbuf, rp, ci);

  const int GB = (N_NODES + 63) / 64;      // 1563 blocks (4 waves x 16 nodes)

  // proj: x @ W0a (fp32 A, K=128) -> hA
  mfma_gemm<4, 1, 0><<<GB, 256, 0, stream>>>(x, nullptr, W0a, nullptr, hA);
  // conv0: agg(hA)+BN+relu -> tile; tile @ W0b + b0b relu -> hB
  conv_fused<1, 0><<<GB, 256, 0, stream>>>(
      hA, rp, ci, b0a, g0, be0,
      nullptr, nullptr, nullptr, nullptr, W0b, b0b, hB, nullptr, nullptr);
  // conv1: agg(hB) -> tile; GEMMa(Wsa0,BN) ; GEMMb(Wsb0) -> hA
  conv_fused<0, 0><<<GB, 256, 0, stream>>>(
      hB, rp, ci, nullptr, nullptr, nullptr,
      Wsa, bsa, gs, bes, Wsb, bsb, hA, nullptr, nullptr);
  // conv2: agg(hA) -> tile; GEMMa(Wsa1,BN) ; GEMMb(Wsb1) + pool -> hp
  conv_fused<0, 1><<<GB, 256, 0, stream>>>(
      hA, rp, ci, nullptr, nullptr, nullptr,
      Wsa + 4096, bsa + 64, gs + 64, bes + 64, Wsb + 4096, bsb + 64,
      nullptr, bat, hp);

  cls_kernel<<<N_GRAPHS, 64, 0, stream>>>(hp, Wl1, bl1, Wl2, bl2, (float*)d_out);
}

// Round 13
// 250.801 us; speedup vs baseline: 1.3218x; 1.3218x over previous
//
#include <hip/hip_runtime.h>

#define N_NODES 100000
#define N_EDGES 1600000
#define IN_DIM 128
#define DIM_H 64
#define N_GRAPHS 64

#define BKT_BITS 9
#define BKT_SIZE 512
#define NBUCKET ((N_NODES + BKT_SIZE - 1) / BKT_SIZE)  /* 196 */
#define NBLK 256
#define EPB ((N_EDGES + NBLK - 1) / NBLK)              /* 6250 */

__device__ __forceinline__ float relu(float v) { return v > 0.f ? v : 0.f; }
#define BN_SCALE 0.99999500003749968f  /* 1/sqrt(1+1e-5) */

typedef __attribute__((ext_vector_type(8))) short bf16x8;
typedef __attribute__((ext_vector_type(4))) float f32x4;

__device__ __forceinline__ float bf2f(unsigned short u) {
  return __uint_as_float(((unsigned int)u) << 16);
}
__device__ __forceinline__ unsigned short f2bf(float f) {
  unsigned int u = __float_as_uint(f);
  u += 0x7FFFu + ((u >> 16) & 1u);   // round-to-nearest-even
  return (unsigned short)(u >> 16);
}

// ---------------- merged: edge_count (blocks 0..255) + proj x@W0a (rest) ----------------
__global__ __launch_bounds__(256) void ec_proj(const int* __restrict__ dst,
                                               int* __restrict__ cnt,
                                               const float* __restrict__ x,
                                               const float* __restrict__ W0a,
                                               unsigned short* __restrict__ hb) {
  __shared__ char smem[128 * 64 * 2];   // union: hist (3.1 KB) / lw (16 KB)
  int tid = threadIdx.x;
  if (blockIdx.x < NBLK) {
    int* hist = (int*)smem;
    int blk = blockIdx.x;
    for (int i = tid; i < 4 * NBUCKET; i += 256) hist[i] = 0;
    __syncthreads();
    int* h = hist + (tid >> 6) * NBUCKET;
    int beg = blk * EPB, end = beg + EPB > N_EDGES ? N_EDGES : beg + EPB;
    for (int i = beg + tid; i < end; i += 256) atomicAdd(&h[dst[i] >> BKT_BITS], 1);
    __syncthreads();
    for (int i = tid; i < 4 * NBUCKET; i += 256) cnt[blk * 4 * NBUCKET + i] = hist[i];
    return;
  }
  // ---- proj: [N_NODES x 128] @ W0a[128 x 64] -> bf16 hb ----
  unsigned short* lw = (unsigned short*)smem;
#pragma unroll
  for (int i = 0; i < 32; ++i) {
    int idx = tid + i * 256;
    int k = idx >> 6, o = idx & 63;
    unsigned int boff = (unsigned int)((o * 128 + k) * 2) ^ ((unsigned int)(o & 7) << 4);
    *(unsigned short*)((char*)lw + boff) = f2bf(W0a[idx]);
  }
  __syncthreads();
  int lane = tid & 63;
  int wave = tid >> 6;
  int arow = lane & 15;
  int kq = lane >> 4;
  int mb = (blockIdx.x - NBLK) * 64 + wave * 16;
  if (mb >= N_NODES) return;
  int anode = mb + arow;
  if (anode >= N_NODES) anode = N_NODES - 1;
  f32x4 acc[4];
#pragma unroll
  for (int t = 0; t < 4; ++t) acc[t] = (f32x4){0.f, 0.f, 0.f, 0.f};
#pragma unroll
  for (int kc = 0; kc < 4; ++kc) {
    const float* ap = x + (size_t)anode * 128 + kc * 32 + kq * 8;
    float4 u0 = *(const float4*)(ap);
    float4 u1 = *(const float4*)(ap + 4);
    bf16x8 afrag;
    afrag[0] = (short)f2bf(u0.x); afrag[1] = (short)f2bf(u0.y);
    afrag[2] = (short)f2bf(u0.z); afrag[3] = (short)f2bf(u0.w);
    afrag[4] = (short)f2bf(u1.x); afrag[5] = (short)f2bf(u1.y);
    afrag[6] = (short)f2bf(u1.z); afrag[7] = (short)f2bf(u1.w);
#pragma unroll
    for (int t = 0; t < 4; ++t) {
      int o = t * 16 + (lane & 15);
      unsigned int boff = (unsigned int)((o * 128 + kc * 32 + kq * 8) * 2) ^
                          ((unsigned int)(o & 7) << 4);
      bf16x8 bfrag = *(const bf16x8*)((char*)lw + boff);
      acc[t] = __builtin_amdgcn_mfma_f32_16x16x32_bf16(afrag, bfrag, acc[t], 0, 0, 0);
    }
  }
  int ccol = lane & 15;
#pragma unroll
  for (int t = 0; t < 4; ++t) {
    int c = t * 16 + ccol;
#pragma unroll
    for (int r = 0; r < 4; ++r) {
      int node = mb + kq * 4 + r;
      if (node < N_NODES) hb[(size_t)node * 64 + c] = f2bf(acc[t][r]);
    }
  }
}

// ---------------- CSR build (rest) ----------------
__global__ __launch_bounds__(256) void col_scan(int* __restrict__ cnt,
                                                int* __restrict__ tot) {
  __shared__ int sd[256];
  int b = blockIdx.x, tid = threadIdx.x;
  int v0 = cnt[(4 * tid + 0) * NBUCKET + b];
  int v1 = cnt[(4 * tid + 1) * NBUCKET + b];
  int v2 = cnt[(4 * tid + 2) * NBUCKET + b];
  int v3 = cnt[(4 * tid + 3) * NBUCKET + b];
  int s = v0 + v1 + v2 + v3;
  sd[tid] = s;
  __syncthreads();
  for (int off = 1; off < 256; off <<= 1) {
    int t = (tid >= off) ? sd[tid - off] : 0;
    __syncthreads();
    sd[tid] += t;
    __syncthreads();
  }
  int excl = sd[tid] - s;
  cnt[(4 * tid + 0) * NBUCKET + b] = excl;
  cnt[(4 * tid + 1) * NBUCKET + b] = excl + v0;
  cnt[(4 * tid + 2) * NBUCKET + b] = excl + v0 + v1;
  cnt[(4 * tid + 3) * NBUCKET + b] = excl + v0 + v1 + v2;
  if (tid == 255) tot[b] = sd[255];
}

__global__ void base_scan(const int* __restrict__ tot, int* __restrict__ base) {
  __shared__ int sd[256];
  int tid = threadIdx.x;
  int v = (tid < NBUCKET) ? tot[tid] : 0;
  sd[tid] = v;
  __syncthreads();
  for (int off = 1; off < 256; off <<= 1) {
    int t = (tid >= off) ? sd[tid - off] : 0;
    __syncthreads();
    sd[tid] += t;
    __syncthreads();
  }
  if (tid < NBUCKET) base[tid] = sd[tid] - v;
}

__global__ __launch_bounds__(256) void edge_place(const int* __restrict__ src,
                                                  const int* __restrict__ dst,
                                                  const int* __restrict__ cnt,
                                                  const int* __restrict__ base,
                                                  int* __restrict__ bktbuf) {
  __shared__ int curs[4 * NBUCKET];
  int tid = threadIdx.x, blk = blockIdx.x;
  for (int i = tid; i < 4 * NBUCKET; i += 256)
    curs[i] = base[i % NBUCKET] + cnt[blk * 4 * NBUCKET + i];
  __syncthreads();
  int* cw = curs + (tid >> 6) * NBUCKET;
  int beg = blk * EPB, end = beg + EPB > N_EDGES ? N_EDGES : beg + EPB;
  for (int i = beg + tid; i < end; i += 256) {
    int d = dst[i];
    int b = d >> BKT_BITS;
    int pos = atomicAdd(&cw[b], 1);
    bktbuf[pos] = src[i] | ((d & (BKT_SIZE - 1)) << 17);
  }
}

__global__ __launch_bounds__(256) void bucket_sort(const int* __restrict__ tot,
                                                   const int* __restrict__ bktbase,
                                                   const int* __restrict__ bktbuf,
                                                   int* __restrict__ rp,
                                                   int* __restrict__ ci) {
  __shared__ int hist[BKT_SIZE];
  __shared__ int partial[256];
  int b = blockIdx.x;
  int tid = threadIdx.x;
  int nb = tot[b];
  int base = bktbase[b];
  const int* buf = bktbuf + base;
  hist[tid] = 0;
  hist[tid + 256] = 0;
  __syncthreads();
  for (int i = tid; i < nb; i += 256) atomicAdd(&hist[buf[i] >> 17], 1);
  __syncthreads();
  int v0 = hist[2 * tid], v1 = hist[2 * tid + 1];
  int s = v0 + v1;
  partial[tid] = s;
  __syncthreads();
  for (int off = 1; off < 256; off <<= 1) {
    int t = (tid >= off) ? partial[tid - off] : 0;
    __syncthreads();
    partial[tid] += t;
    __syncthreads();
  }
  int excl = partial[tid] - s;
  int node0 = b * BKT_SIZE + 2 * tid;
  if (node0 < N_NODES) rp[node0] = base + excl;
  if (node0 + 1 < N_NODES) rp[node0 + 1] = base + excl + v0;
  __syncthreads();
  hist[2 * tid] = excl;
  hist[2 * tid + 1] = excl + v0;
  __syncthreads();
  for (int i = tid; i < nb; i += 256) {
    int p = buf[i];
    int pos = atomicAdd(&hist[p >> 17], 1);
    ci[base + pos] = p & 0x1FFFF;
  }
  if (b == 0 && tid == 0) rp[N_NODES] = N_EDGES;
}

// ---------------- aggregation: R10 4-edge ushort4 layout (48.6 us measured) ----------------
template <int EPI01>
__global__ __launch_bounds__(256) void agg_kernel(const unsigned short* __restrict__ hb,
                                                  const int* __restrict__ rp,
                                                  const int* __restrict__ ci,
                                                  const float* __restrict__ ba,
                                                  const float* __restrict__ g,
                                                  const float* __restrict__ be,
                                                  unsigned short* __restrict__ zb) {
  int wid = (blockIdx.x * 256 + threadIdx.x) >> 6;
  if (wid >= N_NODES) return;
  int lane = threadIdx.x & 63;
  int eg = lane >> 4;
  int dq = lane & 15;
  int beg = rp[wid], end = rp[wid + 1];
  float q0[4] = {0.f, 0.f, 0.f, 0.f};
  float q1[4] = {0.f, 0.f, 0.f, 0.f};
  float q2[4] = {0.f, 0.f, 0.f, 0.f};
  float q3[4] = {0.f, 0.f, 0.f, 0.f};
  int e = beg;
  for (; e + 16 <= end; e += 16) {
    int i0 = ci[e + eg];
    int i1 = ci[e + 4 + eg];
    int i2 = ci[e + 8 + eg];
    int i3 = ci[e + 12 + eg];
    ushort4 v0 = *(const ushort4*)(hb + (size_t)i0 * 64 + dq * 4);
    ushort4 v1 = *(const ushort4*)(hb + (size_t)i1 * 64 + dq * 4);
    ushort4 v2 = *(const ushort4*)(hb + (size_t)i2 * 64 + dq * 4);
    ushort4 v3 = *(const ushort4*)(hb + (size_t)i3 * 64 + dq * 4);
    q0[0] += bf2f(v0.x); q0[1] += bf2f(v0.y); q0[2] += bf2f(v0.z); q0[3] += bf2f(v0.w);
    q1[0] += bf2f(v1.x); q1[1] += bf2f(v1.y); q1[2] += bf2f(v1.z); q1[3] += bf2f(v1.w);
    q2[0] += bf2f(v2.x); q2[1] += bf2f(v2.y); q2[2] += bf2f(v2.z); q2[3] += bf2f(v2.w);
    q3[0] += bf2f(v3.x); q3[1] += bf2f(v3.y); q3[2] += bf2f(v3.z); q3[3] += bf2f(v3.w);
  }
  for (; e + 8 <= end; e += 8) {
    int i0 = ci[e + eg];
    int i1 = ci[e + 4 + eg];
    ushort4 v0 = *(const ushort4*)(hb + (size_t)i0 * 64 + dq * 4);
    ushort4 v1 = *(const ushort4*)(hb + (size_t)i1 * 64 + dq * 4);
    q0[0] += bf2f(v0.x); q0[1] += bf2f(v0.y); q0[2] += bf2f(v0.z); q0[3] += bf2f(v0.w);
    q1[0] += bf2f(v1.x); q1[1] += bf2f(v1.y); q1[2] += bf2f(v1.z); q1[3] += bf2f(v1.w);
  }
  for (; e < end; e += 4) {
    if (e + eg < end) {
      ushort4 v0 = *(const ushort4*)(hb + (size_t)ci[e + eg] * 64 + dq * 4);
      q0[0] += bf2f(v0.x); q0[1] += bf2f(v0.y); q0[2] += bf2f(v0.z); q0[3] += bf2f(v0.w);
    }
  }
  float a0 = (q0[0] + q1[0]) + (q2[0] + q3[0]);
  float a1 = (q0[1] + q1[1]) + (q2[1] + q3[1]);
  float a2 = (q0[2] + q1[2]) + (q2[2] + q3[2]);
  float a3 = (q0[3] + q1[3]) + (q2[3] + q3[3]);
  a0 += __shfl_xor(a0, 16, 64); a1 += __shfl_xor(a1, 16, 64);
  a2 += __shfl_xor(a2, 16, 64); a3 += __shfl_xor(a3, 16, 64);
  a0 += __shfl_xor(a0, 32, 64); a1 += __shfl_xor(a1, 32, 64);
  a2 += __shfl_xor(a2, 32, 64); a3 += __shfl_xor(a3, 32, 64);
  if (eg == 0) {
    ushort4 s = *(const ushort4*)(hb + (size_t)wid * 64 + dq * 4);
    float r0 = a0 + bf2f(s.x), r1 = a1 + bf2f(s.y);
    float r2 = a2 + bf2f(s.z), r3 = a3 + bf2f(s.w);
    if (EPI01) {
      float4 bav = *(const float4*)(ba + dq * 4);
      float4 gv = *(const float4*)(g + dq * 4);
      float4 bev = *(const float4*)(be + dq * 4);
      r0 = relu(fmaf((r0 + bav.x) * BN_SCALE, gv.x, bev.x));
      r1 = relu(fmaf((r1 + bav.y) * BN_SCALE, gv.y, bev.y));
      r2 = relu(fmaf((r2 + bav.z) * BN_SCALE, gv.z, bev.z));
      r3 = relu(fmaf((r3 + bav.w) * BN_SCALE, gv.w, bev.w));
    }
    ushort4 o;
    o.x = f2bf(r0); o.y = f2bf(r1); o.z = f2bf(r2); o.w = f2bf(r3);
    *(ushort4*)(zb + (size_t)wid * 64 + dq * 4) = o;
  }
}

// ---------------- conv0 tail GEMM: zb @ W0b + b0b relu -> hout ----------------
__global__ __launch_bounds__(256) void mfma_gemm1(const unsigned short* __restrict__ ab,
                                                  const float* __restrict__ W,
                                                  const float* __restrict__ bias,
                                                  unsigned short* __restrict__ outb) {
  __shared__ unsigned short lw[64 * 64];
  int tid = threadIdx.x;
#pragma unroll
  for (int i = 0; i < 16; ++i) {
    int idx = tid + i * 256;
    int k = idx >> 6, o = idx & 63;
    unsigned int boff = (unsigned int)((o * 64 + k) * 2) ^ ((unsigned int)(o & 7) << 4);
    *(unsigned short*)((char*)lw + boff) = f2bf(W[idx]);
  }
  __syncthreads();
  int lane = tid & 63;
  int wave = tid >> 6;
  int arow = lane & 15;
  int kq = lane >> 4;
  int mb = blockIdx.x * 64 + wave * 16;
  if (mb >= N_NODES) return;
  int anode = mb + arow;
  if (anode >= N_NODES) anode = N_NODES - 1;
  f32x4 acc[4];
#pragma unroll
  for (int t = 0; t < 4; ++t) acc[t] = (f32x4){0.f, 0.f, 0.f, 0.f};
#pragma unroll
  for (int kc = 0; kc < 2; ++kc) {
    bf16x8 afrag = *(const bf16x8*)(ab + (size_t)anode * 64 + kc * 32 + kq * 8);
#pragma unroll
    for (int t = 0; t < 4; ++t) {
      int o = t * 16 + (lane & 15);
      unsigned int boff = (unsigned int)((o * 64 + kc * 32 + kq * 8) * 2) ^
                          ((unsigned int)(o & 7) << 4);
      bf16x8 bfrag = *(const bf16x8*)((char*)lw + boff);
      acc[t] = __builtin_amdgcn_mfma_f32_16x16x32_bf16(afrag, bfrag, acc[t], 0, 0, 0);
    }
  }
  int ccol = lane & 15;
#pragma unroll
  for (int t = 0; t < 4; ++t) {
    int c = t * 16 + ccol;
    float bv = bias[c];
#pragma unroll
    for (int r = 0; r < 4; ++r) {
      int node = mb + kq * 4 + r;
      if (node < N_NODES) outb[(size_t)node * 64 + c] = f2bf(relu(acc[t][r] + bv));
    }
  }
}

// ---------------- fused double-GEMM: (zb@Wa+ba BN relu) @ Wb + bb relu -> hout/pool ----------------
// GEMMa reads A straight from global zb; t-tile lives in per-wave LDS (no barriers after staging).
template <int LAST>
__global__ __launch_bounds__(256) void gemm2_fused(
    const unsigned short* __restrict__ zb,
    const float* __restrict__ Wa, const float* __restrict__ ba,
    const float* __restrict__ ga, const float* __restrict__ bea,
    const float* __restrict__ Wb, const float* __restrict__ bb,
    unsigned short* __restrict__ hout,
    const int* __restrict__ batch, float* __restrict__ hp) {
  __shared__ unsigned short lwa[64 * 64];
  __shared__ unsigned short lwb[64 * 64];
  __shared__ unsigned short zt[4][16 * 64];
  int tid = threadIdx.x;
#pragma unroll
  for (int i = 0; i < 16; ++i) {
    int idx = tid + i * 256;
    int k = idx >> 6, o = idx & 63;
    unsigned int boff = (unsigned int)((o * 64 + k) * 2) ^ ((unsigned int)(o & 7) << 4);
    *(unsigned short*)((char*)lwa + boff) = f2bf(Wa[idx]);
    *(unsigned short*)((char*)lwb + boff) = f2bf(Wb[idx]);
  }
  __syncthreads();
  int lane = tid & 63;
  int wave = tid >> 6;
  int mb = blockIdx.x * 64 + wave * 16;
  if (mb >= N_NODES) return;
  char* zw = (char*)&zt[wave][0];
  int arow = lane & 15;
  int kq = lane >> 4;
  int ccol = lane & 15;
  int anode = mb + arow;
  if (anode >= N_NODES) anode = N_NODES - 1;
  f32x4 acc[4];

  // GEMMa from global zb
#pragma unroll
  for (int t = 0; t < 4; ++t) acc[t] = (f32x4){0.f, 0.f, 0.f, 0.f};
#pragma unroll
  for (int kc = 0; kc < 2; ++kc) {
    bf16x8 afrag = *(const bf16x8*)(zb + (size_t)anode * 64 + kc * 32 + kq * 8);
#pragma unroll
    for (int t = 0; t < 4; ++t) {
      int o = t * 16 + ccol;
      unsigned int boff = (unsigned int)((o * 64 + kc * 32 + kq * 8) * 2) ^
                          ((unsigned int)(o & 7) << 4);
      bf16x8 bfrag = *(const bf16x8*)((char*)lwa + boff);
      acc[t] = __builtin_amdgcn_mfma_f32_16x16x32_bf16(afrag, bfrag, acc[t], 0, 0, 0);
    }
  }
  // BN + relu -> per-wave tile (swizzled); wave-lockstep, no barrier
#pragma unroll
  for (int t = 0; t < 4; ++t) {
    int c = t * 16 + ccol;
    float bv = ba[c], gv = ga[c], bev = bea[c];
#pragma unroll
    for (int r = 0; r < 4; ++r) {
      int row = kq * 4 + r;
      float v = relu(fmaf((acc[t][r] + bv) * BN_SCALE, gv, bev));
      *(unsigned short*)(zw + ((row * 128 + c * 2) ^ ((row & 7) << 4))) = f2bf(v);
    }
  }
  // GEMMb from tile
#pragma unroll
  for (int t = 0; t < 4; ++t) acc[t] = (f32x4){0.f, 0.f, 0.f, 0.f};
#pragma unroll
  for (int kc = 0; kc < 2; ++kc) {
    bf16x8 afrag = *(const bf16x8*)(zw + ((arow * 128 + kc * 64 + kq * 16) ^ ((arow & 7) << 4)));
#pragma unroll
    for (int t = 0; t < 4; ++t) {
      int o = t * 16 + ccol;
      unsigned int boff = (unsigned int)((o * 64 + kc * 32 + kq * 8) * 2) ^
                          ((unsigned int)(o & 7) << 4);
      bf16x8 bfrag = *(const bf16x8*)((char*)lwb + boff);
      acc[t] = __builtin_amdgcn_mfma_f32_16x16x32_bf16(afrag, bfrag, acc[t], 0, 0, 0);
    }
  }
  if (LAST) {
    int nlast = mb + 15 < N_NODES ? mb + 15 : N_NODES - 1;
    int b0 = batch[mb], b1 = batch[nlast];
    float v[4][4];
#pragma unroll
    for (int t = 0; t < 4; ++t) {
      float bv = bb[t * 16 + ccol];
#pragma unroll
      for (int r = 0; r < 4; ++r) {
        int node = mb + kq * 4 + r;
        v[t][r] = (node < N_NODES) ? relu(acc[t][r] + bv) : 0.f;
      }
    }
    if (b0 == b1) {
#pragma unroll
      for (int t = 0; t < 4; ++t) {
        float s = (v[t][0] + v[t][1]) + (v[t][2] + v[t][3]);
        s += __shfl_xor(s, 16, 64);
        s += __shfl_xor(s, 32, 64);
        if (kq == 0) atomicAdd(&hp[b0 * 64 + t * 16 + ccol], s);
      }
    } else {
      int bn[4];
#pragma unroll
      for (int r = 0; r < 4; ++r) {
        int node = mb + kq * 4 + r;
        bn[r] = batch[node < N_NODES ? node : N_NODES - 1];
      }
#pragma unroll
      for (int t = 0; t < 4; ++t)
#pragma unroll
        for (int r = 0; r < 4; ++r) {
          int node = mb + kq * 4 + r;
          if (node < N_NODES) atomicAdd(&hp[bn[r] * 64 + t * 16 + ccol], v[t][r]);
        }
    }
  } else {
#pragma unroll
    for (int t = 0; t < 4; ++t) {
      int c = t * 16 + ccol;
      float bv = bb[c];
#pragma unroll
      for (int r = 0; r < 4; ++r) {
        int node = mb + kq * 4 + r;
        if (node < N_NODES) hout[(size_t)node * 64 + c] = f2bf(relu(acc[t][r] + bv));
      }
    }
  }
}

// ---------------- classifier ----------------
__global__ __launch_bounds__(64) void cls_kernel(const float* __restrict__ hp,
                                                 const float* __restrict__ Wl1,
                                                 const float* __restrict__ bl1,
                                                 const float* __restrict__ Wl2,
                                                 const float* __restrict__ bl2,
                                                 float* __restrict__ out) {
  int g = blockIdx.x;
  int d = threadIdx.x;
  const float* hrow = hp + g * 64;
  float acc = bl1[d];
#pragma unroll 8
  for (int k = 0; k < 64; ++k) {
    float v = hrow[k];
    float w = Wl1[k * 64 + d] + Wl1[(64 + k) * 64 + d] + Wl1[(128 + k) * 64 + d];
    acc = fmaf(v, w, acc);
  }
  float t = relu(acc);
  float p0 = t * Wl2[d * 2 + 0];
  float p1 = t * Wl2[d * 2 + 1];
#pragma unroll
  for (int off = 32; off > 0; off >>= 1) {
    p0 += __shfl_xor(p0, off, 64);
    p1 += __shfl_xor(p1, off, 64);
  }
  if (d == 0) {
    float z0 = p0 + bl2[0];
    float z1 = p1 + bl2[1];
    float m = fmaxf(z0, z1);
    float lse = m + logf(expf(z0 - m) + expf(z1 - m));
    out[g * 2 + 0] = z0 - lse;
    out[g * 2 + 1] = z1 - lse;
  }
}

extern "C" void kernel_launch(void* const* d_in, const int* in_sizes, int n_in,
                              void* d_out, int out_size, void* d_ws, size_t ws_size,
                              hipStream_t stream) {
  const float* x   = (const float*)d_in[0];
  const int*   ei  = (const int*)d_in[1];
  const int*   bat = (const int*)d_in[2];
  const float* W0a = (const float*)d_in[3];
  const float* b0a = (const float*)d_in[4];
  const float* g0  = (const float*)d_in[5];
  const float* be0 = (const float*)d_in[6];
  const float* W0b = (const float*)d_in[7];
  const float* b0b = (const float*)d_in[8];
  const float* Wsa = (const float*)d_in[9];
  const float* bsa = (const float*)d_in[10];
  const float* gs  = (const float*)d_in[11];
  const float* bes = (const float*)d_in[12];
  const float* Wsb = (const float*)d_in[13];
  const float* bsb = (const float*)d_in[14];
  const float* Wl1 = (const float*)d_in[15];
  const float* bl1 = (const float*)d_in[16];
  const float* Wl2 = (const float*)d_in[17];
  const float* bl2 = (const float*)d_in[18];
  const int* src = ei;
  const int* dst = ei + N_EDGES;

  char* ws = (char*)d_ws;
  size_t off = 0;
  auto alloc = [&](size_t bytes) { void* p = ws + off; off += (bytes + 255) & ~255ull; return p; };
  int* rp      = (int*)alloc((size_t)(N_NODES + 1) * 4);
  int* cnt     = (int*)alloc((size_t)NBLK * 4 * NBUCKET * 4);
  int* tot     = (int*)alloc((size_t)NBUCKET * 4);
  int* bktbase = (int*)alloc((size_t)NBUCKET * 4);
  int* ci      = (int*)alloc((size_t)N_EDGES * 4);
  unsigned short* zb = (unsigned short*)alloc((size_t)N_NODES * 64 * 2);
  unsigned short* hA = (unsigned short*)alloc((size_t)N_NODES * 64 * 2);
  unsigned short* hB = (unsigned short*)alloc((size_t)N_NODES * 64 * 2);
  float* hp    = (float*)alloc((size_t)N_GRAPHS * 64 * 4);
  int* bktbuf  = (int*)hB;  // alias: consumed by bucket_sort before hB first written

  hipMemsetAsync(hp, 0, (size_t)N_GRAPHS * 64 * 4, stream);

  const int GB = (N_NODES + 63) / 64;      // 1563

  // edge_count (blocks 0..255) overlapped with proj -> hA (blocks 256..)
  ec_proj<<<NBLK + GB, 256, 0, stream>>>(dst, cnt, x, W0a, hA);
  col_scan<<<NBUCKET, 256, 0, stream>>>(cnt, tot);
  base_scan<<<1, 256, 0, stream>>>(tot, bktbase);
  edge_place<<<NBLK, 256, 0, stream>>>(src, dst, cnt, bktbase, bktbuf);
  bucket_sort<<<NBUCKET, 256, 0, stream>>>(tot, bktbase, bktbuf, rp, ci);

  const int AB = (N_NODES + 3) / 4;        // 25000

  // conv0
  agg_kernel<1><<<AB, 256, 0, stream>>>(hA, rp, ci, b0a, g0, be0, zb);
  mfma_gemm1<<<GB, 256, 0, stream>>>(zb, W0b, b0b, hB);
  // conv1
  agg_kernel<0><<<AB, 256, 0, stream>>>(hB, rp, ci, nullptr, nullptr, nullptr, zb);
  gemm2_fused<0><<<GB, 256, 0, stream>>>(zb, Wsa, bsa, gs, bes, Wsb, bsb, hA,
                                         nullptr, nullptr);
  // conv2 (+pool)
  agg_kernel<0><<<AB, 256, 0, stream>>>(hA, rp, ci, nullptr, nullptr, nullptr, zb);
  gemm2_fused<1><<<GB, 256, 0, stream>>>(zb, Wsa + 4096, bsa + 64, gs + 64, bes + 64,
                                         Wsb + 4096, bsb + 64, nullptr, bat, hp);

  cls_kernel<<<N_GRAPHS, 64, 0, stream>>>(hp, Wl1, bl1, Wl2, bl2, (float*)d_out);
}